// Round 5
// baseline (84.322 us; speedup 1.0000x reference)
//
#include <hip/hip_runtime.h>

#define IMG 512
#define NPIX (IMG*IMG)
#define NBLK 256

// ---------------------------------------------------------------------------
// Single ordinary kernel, 256 blocks x 256 threads, __launch_bounds__(256,2)
// => VGPR<=256 => >=2 blocks/CU capacity (512 slots) => all 256 blocks
// co-resident: software grid barrier is deadlock-free. No cooperative API.
//
// Phase A: lag Gram partials (320 units looped over 256 blocks).
//          part[(unit)*32 + slot], unit = b*160 + dyi*32 + bx.
// BARRIER: ws counter (memset to 0 each call), release-add / acquire-spin.
// Phase B: EVERY block redundantly reduces part -> L -> attn -> folded
//          3x3 taps, kept in LDS (no second barrier, no AB global trip).
// Phase C: out = x + conv3x3(x0;A) + conv3x3(x1;B), 2 quad-pixels/thread.
// ---------------------------------------------------------------------------
__global__ __launch_bounds__(256,2) void fused_kernel(
    const float* __restrict__ x, const float* __restrict__ e,
    const float* __restrict__ w_conv1, const float* __restrict__ w_dw,
    const float* __restrict__ w_ehead, const float* __restrict__ w_proj,
    const float* __restrict__ a1,
    float* __restrict__ part, unsigned int* __restrict__ bar,
    float* __restrict__ out)
{
  const int blk = blockIdx.x;
  const int tid = threadIdx.x;

  __shared__ float red[4][30];
  __shared__ float Lred[2][150];
  __shared__ float we_lds[128][9];
  __shared__ float nk_lds[2][128];
  __shared__ float attn_lds[2][8][16][16];
  __shared__ float M_lds[2][2][128];
  __shared__ float AB_lds[2][2][2][9];   // [b][o][A/B][tap]

  // ----------------------------- Phase A: gram -----------------------------
  for (int u = blk; u < 320; u += NBLK){
    const int bx  = u & 31;
    const int dyi = (u >> 5) % 5;
    const int dy  = dyi - 2;
    const int b   = u / 160;
    const int half= tid >> 7;
    const int cx  = (tid & 127) << 2;
    const int r0  = (bx << 4) + (half << 3);
    const float* x0 = x + (size_t)b*2*NPIX;
    const float* x1 = x0 + NPIX;
    const float* ep = e + (size_t)b*NPIX;

    float acc[6][5];
#pragma unroll
    for (int t=0;t<6;t++)
#pragma unroll
      for (int j=0;j<5;j++) acc[t][j]=0.f;

    const bool okL = (cx >= 4), okR = (cx < 508);

#pragma unroll 2
    for (int s=0;s<8;s++){
      const int r = r0+s;
      const float4 a0 = *(const float4*)(x0 + r*IMG + cx);
      const float4 a1v= *(const float4*)(x1 + r*IMG + cx);
      const float4 aE = *(const float4*)(ep + r*IMG + cx);
      const int rb = r+dy;
      if ((unsigned)rb < (unsigned)IMG){
        const float* p0 = x0 + rb*IMG;
        const float* p1 = x1 + rb*IMG;
        const float* pe = ep + rb*IMG;
        float w0[8], w1[8], wE[8];
        {
          const float4 z = make_float4(0.f,0.f,0.f,0.f);
          float4 L,M,R;
          L = okL ? *(const float4*)(p0+cx-4) : z;
          M = *(const float4*)(p0+cx);
          R = okR ? *(const float4*)(p0+cx+4) : z;
          w0[0]=L.z;w0[1]=L.w;w0[2]=M.x;w0[3]=M.y;w0[4]=M.z;w0[5]=M.w;w0[6]=R.x;w0[7]=R.y;
          L = okL ? *(const float4*)(p1+cx-4) : z;
          M = *(const float4*)(p1+cx);
          R = okR ? *(const float4*)(p1+cx+4) : z;
          w1[0]=L.z;w1[1]=L.w;w1[2]=M.x;w1[3]=M.y;w1[4]=M.z;w1[5]=M.w;w1[6]=R.x;w1[7]=R.y;
          L = okL ? *(const float4*)(pe+cx-4) : z;
          M = *(const float4*)(pe+cx);
          R = okR ? *(const float4*)(pe+cx+4) : z;
          wE[0]=L.z;wE[1]=L.w;wE[2]=M.x;wE[3]=M.y;wE[4]=M.z;wE[5]=M.w;wE[6]=R.x;wE[7]=R.y;
        }
#pragma unroll
        for (int j=0;j<5;j++){
          acc[0][j] += a0.x*w0[j] + a0.y*w0[j+1] + a0.z*w0[j+2] + a0.w*w0[j+3];
          acc[1][j] += a0.x*w1[j] + a0.y*w1[j+1] + a0.z*w1[j+2] + a0.w*w1[j+3];
          acc[2][j] += a1v.x*w1[j] + a1v.y*w1[j+1] + a1v.z*w1[j+2] + a1v.w*w1[j+3];
          acc[3][j] += a0.x*wE[j] + a0.y*wE[j+1] + a0.z*wE[j+2] + a0.w*wE[j+3];
          acc[4][j] += a1v.x*wE[j] + a1v.y*wE[j+1] + a1v.z*wE[j+2] + a1v.w*wE[j+3];
          acc[5][j] += aE.x*wE[j] + aE.y*wE[j+1] + aE.z*wE[j+2] + aE.w*wE[j+3];
        }
      }
    }

    const int wv   = tid >> 6;
    const int lane = tid & 63;
#pragma unroll
    for (int t=0;t<6;t++)
#pragma unroll
      for (int j=0;j<5;j++){
        float v = acc[t][j];
        for (int off=32; off; off>>=1) v += __shfl_down(v, off);
        if (lane==0) red[wv][t*5+j] = v;
      }
    __syncthreads();
    if (tid < 30)
      part[(size_t)u*32 + tid] = red[0][tid]+red[1][tid]+red[2][tid]+red[3][tid];
    __syncthreads();   // protect red[] before next unit's reduce
  }

  // ------------------------ software grid barrier --------------------------
  // __syncthreads (s_waitcnt vmcnt(0)) above guarantees this block's part
  // stores completed; thread 0: device-scope release (wbL2) + arrive + spin.
  if (tid == 0){
    __threadfence();
    __hip_atomic_fetch_add(bar, 1u, __ATOMIC_RELEASE, __HIP_MEMORY_SCOPE_AGENT);
    while (__hip_atomic_load(bar, __ATOMIC_ACQUIRE, __HIP_MEMORY_SCOPE_AGENT) < NBLK) { }
  }
  __syncthreads();

  // ------------------- Phase B: attn (redundant per block) -----------------
  {
    for (int i=tid; i<300; i+=256){
      const int bb=i/150, li=i%150;
      const int t=li/25, lag=li%25, dyi=lag/5, dxi=lag%5;
      const int u0 = bb*160 + dyi*32;     // bx=0
      const float* p = part + (size_t)u0*32 + t*5+dxi;
      float s=0.f;
#pragma unroll
      for (int j=0;j<32;j++) s += p[j*32];
      Lred[bb][li]=s;
    }
    if (tid<128){
#pragma unroll
      for (int t=0;t<9;t++) we_lds[tid][t]=w_ehead[tid*9+t];
    }
    __syncthreads();

    const int b=tid>>7, h=(tid>>4)&7, c=tid&15;
    const int C=h*16+c;
    const float* Lb  = Lred[b];
    const float* L00=Lb, *L01=Lb+25, *L11=Lb+50, *L0e=Lb+75, *L1e=Lb+100, *Lee=Lb+125;

    float u[9], v[9];
    {
      const float wa=w_conv1[C*2+0], wb=w_conv1[C*2+1];
#pragma unroll
      for (int t=0;t<9;t++){ const float wd=w_dw[C*9+t]; u[t]=wd*wa; v[t]=wd*wb; }
    }
    float nq2=0.f, nk2=0.f;
#pragma unroll
    for (int t=0;t<9;t++){
      const int ty=t/3, tx=t%3;
#pragma unroll
      for (int t2=0;t2<9;t2++){
        const int dy=t2/3-ty, dx=t2%3-tx;
        const int di=( dy+2)*5+( dx+2);
        const int dj=(-dy+2)*5+(-dx+2);
        nq2 += u[t]*u[t2]*L00[di] + u[t]*v[t2]*L01[di] + v[t]*u[t2]*L01[dj] + v[t]*v[t2]*L11[di];
        nk2 += we_lds[C][t]*we_lds[C][t2]*Lee[di];
      }
    }
    nk_lds[b][C]=sqrtf(nk2);
    float P[9];
#pragma unroll
    for (int t2=0;t2<9;t2++){
      float s=0.f;
      const int t2y=t2/3, t2x=t2%3;
#pragma unroll
      for (int t=0;t<9;t++){
        const int di=(t2y-t/3+2)*5+(t2x-t%3+2);
        s += u[t]*L0e[di] + v[t]*L1e[di];
      }
      P[t2]=s;
    }
    __syncthreads();
    const float inv_nq = 1.f/fmaxf(sqrtf(nq2), 1e-12f);
    const float a1h=a1[h];
    float lg[16], mx=-1e30f;
#pragma unroll
    for (int d=0; d<16; d++){
      float S=0.f;
#pragma unroll
      for (int t2=0;t2<9;t2++) S += P[t2]*we_lds[h*16+d][t2];
      const float l = S*inv_nq/fmaxf(nk_lds[b][h*16+d],1e-12f)*a1h;
      lg[d]=l; mx=fmaxf(mx,l);
    }
    float sum=0.f;
#pragma unroll
    for (int d=0;d<16;d++){ lg[d]=expf(lg[d]-mx); sum+=lg[d]; }
    const float inv=1.f/sum;
#pragma unroll
    for (int d=0;d<16;d++) attn_lds[b][h][c][d]=lg[d]*inv;
    __syncthreads();
    for (int i=tid;i<512;i+=256){
      const int G=i&127, o=(i>>7)&1, bb=i>>8;
      const int hh=G>>4, dd=G&15;
      float s=0.f;
#pragma unroll
      for (int cc=0;cc<16;cc++) s += w_proj[o*128 + hh*16+cc]*attn_lds[bb][hh][cc][dd];
      M_lds[bb][o][G]=s;
    }
    __syncthreads();
    if (tid<36){
      const int t=tid%9, o=(tid/9)&1, bb=tid/18;
      float sa=0.f, sb=0.f;
      for (int G=0;G<128;G++){
        const float m=M_lds[bb][o][G];
        const float wd=w_dw[(128+G)*9+t];
        sa += m*wd*w_conv1[(128+G)*2+0];
        sb += m*wd*w_conv1[(128+G)*2+1];
      }
      AB_lds[bb][o][0][t] = sa;
      AB_lds[bb][o][1][t] = sb;
    }
    __syncthreads();
  }

  // ----------------------------- Phase C: out ------------------------------
#pragma unroll
  for (int it=0; it<2; ++it){
    const int idx = it*65536 + blk*256 + tid;   // 131072 total positions
    const int b  = idx >> 16;
    const int y  = (idx >> 7) & (IMG-1);
    const int xc = (idx & 127) << 2;
    const float* x0 = x + (size_t)b*2*NPIX;
    const float* x1 = x0 + NPIX;

    float A0[9],A1[9],B0[9],B1[9];
#pragma unroll
    for (int t=0;t<9;t++){
      A0[t]=AB_lds[b][0][0][t];  A1[t]=AB_lds[b][1][0][t];
      B0[t]=AB_lds[b][0][1][t];  B1[t]=AB_lds[b][1][1][t];
    }
    float v0[3][6], v1[3][6];
#pragma unroll
    for (int r=0;r<3;r++){
      const int yy=y-1+r;
      if ((unsigned)yy < (unsigned)IMG){
        const float* p0=x0+(size_t)yy*IMG;
        const float* p1=x1+(size_t)yy*IMG;
        const float4 m0=*(const float4*)(p0+xc);
        const float4 m1=*(const float4*)(p1+xc);
        v0[r][1]=m0.x; v0[r][2]=m0.y; v0[r][3]=m0.z; v0[r][4]=m0.w;
        v1[r][1]=m1.x; v1[r][2]=m1.y; v1[r][3]=m1.z; v1[r][4]=m1.w;
        v0[r][0]=(xc>0)?p0[xc-1]:0.f;        v1[r][0]=(xc>0)?p1[xc-1]:0.f;
        v0[r][5]=(xc+4<IMG)?p0[xc+4]:0.f;    v1[r][5]=(xc+4<IMG)?p1[xc+4]:0.f;
      } else {
#pragma unroll
        for (int c2=0;c2<6;c2++){v0[r][c2]=0.f;v1[r][c2]=0.f;}
      }
    }
    float res0[4], res1[4];
#pragma unroll
    for (int i=0;i<4;i++){
      float s0=v0[1][i+1];
      float s1=v1[1][i+1];
#pragma unroll
      for (int t=0;t<9;t++){
        const int ty=t/3, tx=t%3;
        const float g0=v0[ty][i+tx], g1=v1[ty][i+tx];
        s0 += A0[t]*g0 + B0[t]*g1;
        s1 += A1[t]*g0 + B1[t]*g1;
      }
      res0[i]=s0; res1[i]=s1;
    }
    float* o0p = out + ((size_t)(b*2+0)*IMG + y)*IMG + xc;
    float* o1p = out + ((size_t)(b*2+1)*IMG + y)*IMG + xc;
    *(float4*)o0p = make_float4(res0[0],res0[1],res0[2],res0[3]);
    *(float4*)o1p = make_float4(res1[0],res1[1],res1[2],res1[3]);
  }
}

extern "C" void kernel_launch(void* const* d_in, const int* in_sizes, int n_in,
                              void* d_out, int out_size, void* d_ws, size_t ws_size,
                              hipStream_t stream){
  const float* x       = (const float*)d_in[0];
  const float* e       = (const float*)d_in[1];
  const float* w_conv1 = (const float*)d_in[2];
  const float* w_dw    = (const float*)d_in[3];
  const float* w_ehead = (const float*)d_in[4];
  const float* w_proj  = (const float*)d_in[5];
  const float* a1      = (const float*)d_in[6];
  float* ws   = (float*)d_ws;
  float* part = ws;                              // 320*32 = 10240 floats
  unsigned int* bar = (unsigned int*)(ws + 10240);
  float* out  = (float*)d_out;

  hipMemsetAsync(bar, 0, sizeof(unsigned int), stream);
  hipLaunchKernelGGL(fused_kernel, dim3(NBLK), dim3(256), 0, stream,
                     x, e, w_conv1, w_dw, w_ehead, w_proj, a1, part, bar, out);
}

// Round 6
// 78.144 us; speedup vs baseline: 1.0791x; 1.0791x over previous
//
#include <hip/hip_runtime.h>

#define IMG 512
#define NPIX (IMG*IMG)
#define NBLK 256

// ---------------------------------------------------------------------------
// Single ordinary kernel, 256 blocks x 256 threads, __launch_bounds__(256,2)
// => all 256 blocks co-resident (2 blocks/CU capacity): software grid barrier
// is deadlock-free without the cooperative API.
//
// Phase A: lag Gram partials. 640 units (2b x 5dy x 64 strips of 8 rows),
//          <=3 units/block (vs 2) so barrier skew ~ half a unit.
// BARRIER: arrive = release atomicAdd; spin = RELAXED load + s_sleep backoff
//          (R5 lesson: ACQUIRE-per-poll emits a cache-invalidate each
//          iteration -> 256 spinners nuke L1/L2 across XCDs -> 75us stall);
//          one acquire fence after exit.
// Phase B: every block redundantly reduces part -> L -> attn -> folded 3x3
//          taps, kept in LDS.
// Phase C: out = x + conv3x3(x0;A) + conv3x3(x1;B), 2 quad-pixels/thread.
// ---------------------------------------------------------------------------
__global__ __launch_bounds__(256,2) void fused_kernel(
    const float* __restrict__ x, const float* __restrict__ e,
    const float* __restrict__ w_conv1, const float* __restrict__ w_dw,
    const float* __restrict__ w_ehead, const float* __restrict__ w_proj,
    const float* __restrict__ a1,
    float* __restrict__ part, unsigned int* __restrict__ bar,
    float* __restrict__ out)
{
  const int blk = blockIdx.x;
  const int tid = threadIdx.x;

  __shared__ float red[4][30];
  __shared__ float Lred[2][150];
  __shared__ float we_lds[128][9];
  __shared__ float nk_lds[2][128];
  __shared__ float attn_lds[2][8][16][16];
  __shared__ float M_lds[2][2][128];
  __shared__ float AB_lds[2][2][2][9];   // [b][o][A/B][tap]

  // ----------------------------- Phase A: gram -----------------------------
  for (int u = blk; u < 640; u += NBLK){
    const int strip = u & 63;
    const int dyi = (u >> 6) % 5;
    const int dy  = dyi - 2;
    const int b   = u / 320;
    const int half= tid >> 7;
    const int cx  = (tid & 127) << 2;
    const int r0  = (strip << 3) + (half << 2);    // 4 rows per thread
    const float* x0 = x + (size_t)b*2*NPIX;
    const float* x1 = x0 + NPIX;
    const float* ep = e + (size_t)b*NPIX;

    float acc[6][5];
#pragma unroll
    for (int t=0;t<6;t++)
#pragma unroll
      for (int j=0;j<5;j++) acc[t][j]=0.f;

    const bool okL = (cx >= 4), okR = (cx < 508);

#pragma unroll 2
    for (int s=0;s<4;s++){
      const int r = r0+s;
      const float4 a0 = *(const float4*)(x0 + r*IMG + cx);
      const float4 a1v= *(const float4*)(x1 + r*IMG + cx);
      const float4 aE = *(const float4*)(ep + r*IMG + cx);
      const int rb = r+dy;
      if ((unsigned)rb < (unsigned)IMG){
        const float* p0 = x0 + rb*IMG;
        const float* p1 = x1 + rb*IMG;
        const float* pe = ep + rb*IMG;
        float w0[8], w1[8], wE[8];
        {
          const float4 z = make_float4(0.f,0.f,0.f,0.f);
          float4 L,M,R;
          L = okL ? *(const float4*)(p0+cx-4) : z;
          M = *(const float4*)(p0+cx);
          R = okR ? *(const float4*)(p0+cx+4) : z;
          w0[0]=L.z;w0[1]=L.w;w0[2]=M.x;w0[3]=M.y;w0[4]=M.z;w0[5]=M.w;w0[6]=R.x;w0[7]=R.y;
          L = okL ? *(const float4*)(p1+cx-4) : z;
          M = *(const float4*)(p1+cx);
          R = okR ? *(const float4*)(p1+cx+4) : z;
          w1[0]=L.z;w1[1]=L.w;w1[2]=M.x;w1[3]=M.y;w1[4]=M.z;w1[5]=M.w;w1[6]=R.x;w1[7]=R.y;
          L = okL ? *(const float4*)(pe+cx-4) : z;
          M = *(const float4*)(pe+cx);
          R = okR ? *(const float4*)(pe+cx+4) : z;
          wE[0]=L.z;wE[1]=L.w;wE[2]=M.x;wE[3]=M.y;wE[4]=M.z;wE[5]=M.w;wE[6]=R.x;wE[7]=R.y;
        }
#pragma unroll
        for (int j=0;j<5;j++){
          acc[0][j] += a0.x*w0[j] + a0.y*w0[j+1] + a0.z*w0[j+2] + a0.w*w0[j+3];
          acc[1][j] += a0.x*w1[j] + a0.y*w1[j+1] + a0.z*w1[j+2] + a0.w*w1[j+3];
          acc[2][j] += a1v.x*w1[j] + a1v.y*w1[j+1] + a1v.z*w1[j+2] + a1v.w*w1[j+3];
          acc[3][j] += a0.x*wE[j] + a0.y*wE[j+1] + a0.z*wE[j+2] + a0.w*wE[j+3];
          acc[4][j] += a1v.x*wE[j] + a1v.y*wE[j+1] + a1v.z*wE[j+2] + a1v.w*wE[j+3];
          acc[5][j] += aE.x*wE[j] + aE.y*wE[j+1] + aE.z*wE[j+2] + aE.w*wE[j+3];
        }
      }
    }

    const int wv   = tid >> 6;
    const int lane = tid & 63;
#pragma unroll
    for (int t=0;t<6;t++)
#pragma unroll
      for (int j=0;j<5;j++){
        float v = acc[t][j];
        for (int off=32; off; off>>=1) v += __shfl_down(v, off);
        if (lane==0) red[wv][t*5+j] = v;
      }
    __syncthreads();
    if (tid < 30)
      part[(size_t)u*32 + tid] = red[0][tid]+red[1][tid]+red[2][tid]+red[3][tid];
    __syncthreads();   // protect red[] before next unit's reduce
  }

  // ------------------------ software grid barrier --------------------------
  if (tid == 0){
    // release: prior part stores (drained by the __syncthreads above) become
    // agent-visible with the RMW's release ordering.
    __hip_atomic_fetch_add(bar, 1u, __ATOMIC_RELEASE, __HIP_MEMORY_SCOPE_AGENT);
    // spin RELAXED (no per-poll cache invalidate) with sleep backoff.
    while (__hip_atomic_load(bar, __ATOMIC_RELAXED, __HIP_MEMORY_SCOPE_AGENT) < NBLK)
      __builtin_amdgcn_s_sleep(8);
  }
  __syncthreads();
  __builtin_amdgcn_fence(__ATOMIC_ACQUIRE, "agent");  // one inv per wave, not per poll

  // ------------------- Phase B: attn (redundant per block) -----------------
  {
    for (int i=tid; i<300; i+=256){
      const int bb=i/150, li=i%150;
      const int t=li/25, lag=li%25, dyi=lag/5, dxi=lag%5;
      const float* p = part + (size_t)(bb*320 + dyi*64)*32 + t*5+dxi;
      float s=0.f;
#pragma unroll
      for (int j=0;j<64;j++) s += p[j*32];
      Lred[bb][li]=s;
    }
    if (tid<128){
#pragma unroll
      for (int t=0;t<9;t++) we_lds[tid][t]=w_ehead[tid*9+t];
    }
    __syncthreads();

    const int b=tid>>7, h=(tid>>4)&7, c=tid&15;
    const int C=h*16+c;
    const float* Lb  = Lred[b];
    const float* L00=Lb, *L01=Lb+25, *L11=Lb+50, *L0e=Lb+75, *L1e=Lb+100, *Lee=Lb+125;

    float u[9], v[9];
    {
      const float wa=w_conv1[C*2+0], wb=w_conv1[C*2+1];
#pragma unroll
      for (int t=0;t<9;t++){ const float wd=w_dw[C*9+t]; u[t]=wd*wa; v[t]=wd*wb; }
    }
    float nq2=0.f, nk2=0.f;
#pragma unroll
    for (int t=0;t<9;t++){
      const int ty=t/3, tx=t%3;
#pragma unroll
      for (int t2=0;t2<9;t2++){
        const int dy=t2/3-ty, dx=t2%3-tx;
        const int di=( dy+2)*5+( dx+2);
        const int dj=(-dy+2)*5+(-dx+2);
        nq2 += u[t]*u[t2]*L00[di] + u[t]*v[t2]*L01[di] + v[t]*u[t2]*L01[dj] + v[t]*v[t2]*L11[di];
        nk2 += we_lds[C][t]*we_lds[C][t2]*Lee[di];
      }
    }
    nk_lds[b][C]=sqrtf(nk2);
    float P[9];
#pragma unroll
    for (int t2=0;t2<9;t2++){
      float s=0.f;
      const int t2y=t2/3, t2x=t2%3;
#pragma unroll
      for (int t=0;t<9;t++){
        const int di=(t2y-t/3+2)*5+(t2x-t%3+2);
        s += u[t]*L0e[di] + v[t]*L1e[di];
      }
      P[t2]=s;
    }
    __syncthreads();
    const float inv_nq = 1.f/fmaxf(sqrtf(nq2), 1e-12f);
    const float a1h=a1[h];
    float lg[16], mx=-1e30f;
#pragma unroll
    for (int d=0; d<16; d++){
      float S=0.f;
#pragma unroll
      for (int t2=0;t2<9;t2++) S += P[t2]*we_lds[h*16+d][t2];
      const float l = S*inv_nq/fmaxf(nk_lds[b][h*16+d],1e-12f)*a1h;
      lg[d]=l; mx=fmaxf(mx,l);
    }
    float sum=0.f;
#pragma unroll
    for (int d=0;d<16;d++){ lg[d]=expf(lg[d]-mx); sum+=lg[d]; }
    const float inv=1.f/sum;
#pragma unroll
    for (int d=0;d<16;d++) attn_lds[b][h][c][d]=lg[d]*inv;
    __syncthreads();
    for (int i=tid;i<512;i+=256){
      const int G=i&127, o=(i>>7)&1, bb=i>>8;
      const int hh=G>>4, dd=G&15;
      float s=0.f;
#pragma unroll
      for (int cc=0;cc<16;cc++) s += w_proj[o*128 + hh*16+cc]*attn_lds[bb][hh][cc][dd];
      M_lds[bb][o][G]=s;
    }
    __syncthreads();
    if (tid<36){
      const int t=tid%9, o=(tid/9)&1, bb=tid/18;
      float sa=0.f, sb=0.f;
      for (int G=0;G<128;G++){
        const float m=M_lds[bb][o][G];
        const float wd=w_dw[(128+G)*9+t];
        sa += m*wd*w_conv1[(128+G)*2+0];
        sb += m*wd*w_conv1[(128+G)*2+1];
      }
      AB_lds[bb][o][0][t] = sa;
      AB_lds[bb][o][1][t] = sb;
    }
    __syncthreads();
  }

  // ----------------------------- Phase C: out ------------------------------
#pragma unroll
  for (int it=0; it<2; ++it){
    const int idx = it*65536 + blk*256 + tid;   // 131072 total positions
    const int b  = idx >> 16;
    const int y  = (idx >> 7) & (IMG-1);
    const int xc = (idx & 127) << 2;
    const float* x0 = x + (size_t)b*2*NPIX;
    const float* x1 = x0 + NPIX;

    float A0[9],A1[9],B0[9],B1[9];
#pragma unroll
    for (int t=0;t<9;t++){
      A0[t]=AB_lds[b][0][0][t];  A1[t]=AB_lds[b][1][0][t];
      B0[t]=AB_lds[b][0][1][t];  B1[t]=AB_lds[b][1][1][t];
    }
    float v0[3][6], v1[3][6];
#pragma unroll
    for (int r=0;r<3;r++){
      const int yy=y-1+r;
      if ((unsigned)yy < (unsigned)IMG){
        const float* p0=x0+(size_t)yy*IMG;
        const float* p1=x1+(size_t)yy*IMG;
        const float4 m0=*(const float4*)(p0+xc);
        const float4 m1=*(const float4*)(p1+xc);
        v0[r][1]=m0.x; v0[r][2]=m0.y; v0[r][3]=m0.z; v0[r][4]=m0.w;
        v1[r][1]=m1.x; v1[r][2]=m1.y; v1[r][3]=m1.z; v1[r][4]=m1.w;
        v0[r][0]=(xc>0)?p0[xc-1]:0.f;        v1[r][0]=(xc>0)?p1[xc-1]:0.f;
        v0[r][5]=(xc+4<IMG)?p0[xc+4]:0.f;    v1[r][5]=(xc+4<IMG)?p1[xc+4]:0.f;
      } else {
#pragma unroll
        for (int c2=0;c2<6;c2++){v0[r][c2]=0.f;v1[r][c2]=0.f;}
      }
    }
    float res0[4], res1[4];
#pragma unroll
    for (int i=0;i<4;i++){
      float s0=v0[1][i+1];
      float s1=v1[1][i+1];
#pragma unroll
      for (int t=0;t<9;t++){
        const int ty=t/3, tx=t%3;
        const float g0=v0[ty][i+tx], g1=v1[ty][i+tx];
        s0 += A0[t]*g0 + B0[t]*g1;
        s1 += A1[t]*g0 + B1[t]*g1;
      }
      res0[i]=s0; res1[i]=s1;
    }
    float* o0p = out + ((size_t)(b*2+0)*IMG + y)*IMG + xc;
    float* o1p = out + ((size_t)(b*2+1)*IMG + y)*IMG + xc;
    *(float4*)o0p = make_float4(res0[0],res0[1],res0[2],res0[3]);
    *(float4*)o1p = make_float4(res1[0],res1[1],res1[2],res1[3]);
  }
}

extern "C" void kernel_launch(void* const* d_in, const int* in_sizes, int n_in,
                              void* d_out, int out_size, void* d_ws, size_t ws_size,
                              hipStream_t stream){
  const float* x       = (const float*)d_in[0];
  const float* e       = (const float*)d_in[1];
  const float* w_conv1 = (const float*)d_in[2];
  const float* w_dw    = (const float*)d_in[3];
  const float* w_ehead = (const float*)d_in[4];
  const float* w_proj  = (const float*)d_in[5];
  const float* a1      = (const float*)d_in[6];
  float* ws   = (float*)d_ws;
  float* part = ws;                              // 640*32 = 20480 floats
  unsigned int* bar = (unsigned int*)(ws + 20480);
  float* out  = (float*)d_out;

  hipMemsetAsync(bar, 0, sizeof(unsigned int), stream);
  hipLaunchKernelGGL(fused_kernel, dim3(NBLK), dim3(256), 0, stream,
                     x, e, w_conv1, w_dw, w_ehead, w_proj, a1, part, bar, out);
}

// Round 7
// 66.717 us; speedup vs baseline: 1.2639x; 1.1713x over previous
//
#include <hip/hip_runtime.h>

#define IMG 512
#define NPIX (IMG*IMG)
#define NBLK 256

#define ST_AGENT(p, v) __hip_atomic_store((p), (v), __ATOMIC_RELAXED, __HIP_MEMORY_SCOPE_AGENT)
#define LD_AGENT(p)    __hip_atomic_load((p), __ATOMIC_RELAXED, __HIP_MEMORY_SCOPE_AGENT)

// ---------------------------------------------------------------------------
// Single kernel, 256 blocks x 256 threads, all co-resident (1 block/CU).
//
// R6 lesson: agent-scope RELEASE RMW on gfx950 emits buffer_wbl2 (full L2
// writeback, per arriving block!) and acquire emits buffer_inv -- with 256
// blocks that cache maintenance was the ~66us stall. This version does ALL
// cross-block communication with RELAXED agent-scope atomics (sc1 -> L2
// bypassed, data lives in Infinity Cache): part stores are write-through,
// part reads are uncached, barrier is relaxed RMW + relaxed spin. Ordering
// comes from __syncthreads' vmcnt(0) drain (sc1 store ack = at IC).
// No wbl2 / buffer_inv anywhere.
//
// Phase A: lag Gram partials, 640 units (2b x 5dy x 64 strips of 8 rows).
// Phase B: every block redundantly reduces part -> L -> attn -> 3x3 taps in LDS.
// Phase C: out = x + conv3x3(x0;A) + conv3x3(x1;B).
// ---------------------------------------------------------------------------
__global__ __launch_bounds__(256,2) void fused_kernel(
    const float* __restrict__ x, const float* __restrict__ e,
    const float* __restrict__ w_conv1, const float* __restrict__ w_dw,
    const float* __restrict__ w_ehead, const float* __restrict__ w_proj,
    const float* __restrict__ a1,
    float* __restrict__ part, unsigned int* __restrict__ bar,
    float* __restrict__ out)
{
  const int blk = blockIdx.x;
  const int tid = threadIdx.x;

  __shared__ float red[4][30];
  __shared__ float Lred[2][150];
  __shared__ float we_lds[128][9];
  __shared__ float nk_lds[2][128];
  __shared__ float attn_lds[2][8][16][16];
  __shared__ float M_lds[2][2][128];
  __shared__ float AB_lds[2][2][2][9];   // [b][o][A/B][tap]

  // ----------------------------- Phase A: gram -----------------------------
  for (int u = blk; u < 640; u += NBLK){
    const int strip = u & 63;
    const int dyi = (u >> 6) % 5;
    const int dy  = dyi - 2;
    const int b   = u / 320;
    const int half= tid >> 7;
    const int cx  = (tid & 127) << 2;
    const int r0  = (strip << 3) + (half << 2);    // 4 rows per thread
    const float* x0 = x + (size_t)b*2*NPIX;
    const float* x1 = x0 + NPIX;
    const float* ep = e + (size_t)b*NPIX;

    float acc[6][5];
#pragma unroll
    for (int t=0;t<6;t++)
#pragma unroll
      for (int j=0;j<5;j++) acc[t][j]=0.f;

    const bool okL = (cx >= 4), okR = (cx < 508);

#pragma unroll 2
    for (int s=0;s<4;s++){
      const int r = r0+s;
      const float4 a0 = *(const float4*)(x0 + r*IMG + cx);
      const float4 a1v= *(const float4*)(x1 + r*IMG + cx);
      const float4 aE = *(const float4*)(ep + r*IMG + cx);
      const int rb = r+dy;
      if ((unsigned)rb < (unsigned)IMG){
        const float* p0 = x0 + rb*IMG;
        const float* p1 = x1 + rb*IMG;
        const float* pe = ep + rb*IMG;
        float w0[8], w1[8], wE[8];
        {
          const float4 z = make_float4(0.f,0.f,0.f,0.f);
          float4 L,M,R;
          L = okL ? *(const float4*)(p0+cx-4) : z;
          M = *(const float4*)(p0+cx);
          R = okR ? *(const float4*)(p0+cx+4) : z;
          w0[0]=L.z;w0[1]=L.w;w0[2]=M.x;w0[3]=M.y;w0[4]=M.z;w0[5]=M.w;w0[6]=R.x;w0[7]=R.y;
          L = okL ? *(const float4*)(p1+cx-4) : z;
          M = *(const float4*)(p1+cx);
          R = okR ? *(const float4*)(p1+cx+4) : z;
          w1[0]=L.z;w1[1]=L.w;w1[2]=M.x;w1[3]=M.y;w1[4]=M.z;w1[5]=M.w;w1[6]=R.x;w1[7]=R.y;
          L = okL ? *(const float4*)(pe+cx-4) : z;
          M = *(const float4*)(pe+cx);
          R = okR ? *(const float4*)(pe+cx+4) : z;
          wE[0]=L.z;wE[1]=L.w;wE[2]=M.x;wE[3]=M.y;wE[4]=M.z;wE[5]=M.w;wE[6]=R.x;wE[7]=R.y;
        }
#pragma unroll
        for (int j=0;j<5;j++){
          acc[0][j] += a0.x*w0[j] + a0.y*w0[j+1] + a0.z*w0[j+2] + a0.w*w0[j+3];
          acc[1][j] += a0.x*w1[j] + a0.y*w1[j+1] + a0.z*w1[j+2] + a0.w*w1[j+3];
          acc[2][j] += a1v.x*w1[j] + a1v.y*w1[j+1] + a1v.z*w1[j+2] + a1v.w*w1[j+3];
          acc[3][j] += a0.x*wE[j] + a0.y*wE[j+1] + a0.z*wE[j+2] + a0.w*wE[j+3];
          acc[4][j] += a1v.x*wE[j] + a1v.y*wE[j+1] + a1v.z*wE[j+2] + a1v.w*wE[j+3];
          acc[5][j] += aE.x*wE[j] + aE.y*wE[j+1] + aE.z*wE[j+2] + aE.w*wE[j+3];
        }
      }
    }

    const int wv   = tid >> 6;
    const int lane = tid & 63;
#pragma unroll
    for (int t=0;t<6;t++)
#pragma unroll
      for (int j=0;j<5;j++){
        float v = acc[t][j];
        for (int off=32; off; off>>=1) v += __shfl_down(v, off);
        if (lane==0) red[wv][t*5+j] = v;
      }
    __syncthreads();
    if (tid < 30)
      ST_AGENT(&part[(size_t)u*32 + tid],
               red[0][tid]+red[1][tid]+red[2][tid]+red[3][tid]);
    __syncthreads();   // protect red[] before next unit's reduce
  }

  // ------------------------ software grid barrier --------------------------
  // __syncthreads above drained each wave's vmcnt: the sc1 part stores are
  // acked at the Infinity Cache. Relaxed arrive + relaxed spin: zero cache
  // maintenance.
  if (tid == 0){
    __hip_atomic_fetch_add(bar, 1u, __ATOMIC_RELAXED, __HIP_MEMORY_SCOPE_AGENT);
    while (LD_AGENT(bar) < NBLK)
      __builtin_amdgcn_s_sleep(1);
  }
  __syncthreads();

  // ------------------- Phase B: attn (redundant per block) -----------------
  {
    for (int i=tid; i<300; i+=256){
      const int bb=i/150, li=i%150;
      const int t=li/25, lag=li%25, dyi=lag/5, dxi=lag%5;
      float* p = part + (size_t)(bb*320 + dyi*64)*32 + t*5+dxi;
      float s=0.f;
#pragma unroll
      for (int j=0;j<64;j++) s += LD_AGENT(&p[j*32]);
      Lred[bb][li]=s;
    }
    if (tid<128){
#pragma unroll
      for (int t=0;t<9;t++) we_lds[tid][t]=w_ehead[tid*9+t];
    }
    __syncthreads();

    const int b=tid>>7, h=(tid>>4)&7, c=tid&15;
    const int C=h*16+c;
    const float* Lb  = Lred[b];
    const float* L00=Lb, *L01=Lb+25, *L11=Lb+50, *L0e=Lb+75, *L1e=Lb+100, *Lee=Lb+125;

    float u[9], v[9];
    {
      const float wa=w_conv1[C*2+0], wb=w_conv1[C*2+1];
#pragma unroll
      for (int t=0;t<9;t++){ const float wd=w_dw[C*9+t]; u[t]=wd*wa; v[t]=wd*wb; }
    }
    float nq2=0.f, nk2=0.f;
#pragma unroll
    for (int t=0;t<9;t++){
      const int ty=t/3, tx=t%3;
#pragma unroll
      for (int t2=0;t2<9;t2++){
        const int dy=t2/3-ty, dx=t2%3-tx;
        const int di=( dy+2)*5+( dx+2);
        const int dj=(-dy+2)*5+(-dx+2);
        nq2 += u[t]*u[t2]*L00[di] + u[t]*v[t2]*L01[di] + v[t]*u[t2]*L01[dj] + v[t]*v[t2]*L11[di];
        nk2 += we_lds[C][t]*we_lds[C][t2]*Lee[di];
      }
    }
    nk_lds[b][C]=sqrtf(nk2);
    float P[9];
#pragma unroll
    for (int t2=0;t2<9;t2++){
      float s=0.f;
      const int t2y=t2/3, t2x=t2%3;
#pragma unroll
      for (int t=0;t<9;t++){
        const int di=(t2y-t/3+2)*5+(t2x-t%3+2);
        s += u[t]*L0e[di] + v[t]*L1e[di];
      }
      P[t2]=s;
    }
    __syncthreads();
    const float inv_nq = 1.f/fmaxf(sqrtf(nq2), 1e-12f);
    const float a1h=a1[h];
    float lg[16], mx=-1e30f;
#pragma unroll
    for (int d=0; d<16; d++){
      float S=0.f;
#pragma unroll
      for (int t2=0;t2<9;t2++) S += P[t2]*we_lds[h*16+d][t2];
      const float l = S*inv_nq/fmaxf(nk_lds[b][h*16+d],1e-12f)*a1h;
      lg[d]=l; mx=fmaxf(mx,l);
    }
    float sum=0.f;
#pragma unroll
    for (int d=0;d<16;d++){ lg[d]=expf(lg[d]-mx); sum+=lg[d]; }
    const float inv=1.f/sum;
#pragma unroll
    for (int d=0;d<16;d++) attn_lds[b][h][c][d]=lg[d]*inv;
    __syncthreads();
    for (int i=tid;i<512;i+=256){
      const int G=i&127, o=(i>>7)&1, bb=i>>8;
      const int hh=G>>4, dd=G&15;
      float s=0.f;
#pragma unroll
      for (int cc=0;cc<16;cc++) s += w_proj[o*128 + hh*16+cc]*attn_lds[bb][hh][cc][dd];
      M_lds[bb][o][G]=s;
    }
    __syncthreads();
    if (tid<36){
      const int t=tid%9, o=(tid/9)&1, bb=tid/18;
      float sa=0.f, sb=0.f;
      for (int G=0;G<128;G++){
        const float m=M_lds[bb][o][G];
        const float wd=w_dw[(128+G)*9+t];
        sa += m*wd*w_conv1[(128+G)*2+0];
        sb += m*wd*w_conv1[(128+G)*2+1];
      }
      AB_lds[bb][o][0][t] = sa;
      AB_lds[bb][o][1][t] = sb;
    }
    __syncthreads();
  }

  // ----------------------------- Phase C: out ------------------------------
#pragma unroll
  for (int it=0; it<2; ++it){
    const int idx = it*65536 + blk*256 + tid;   // 131072 total positions
    const int b  = idx >> 16;
    const int y  = (idx >> 7) & (IMG-1);
    const int xc = (idx & 127) << 2;
    const float* x0 = x + (size_t)b*2*NPIX;
    const float* x1 = x0 + NPIX;

    float A0[9],A1[9],B0[9],B1[9];
#pragma unroll
    for (int t=0;t<9;t++){
      A0[t]=AB_lds[b][0][0][t];  A1[t]=AB_lds[b][1][0][t];
      B0[t]=AB_lds[b][0][1][t];  B1[t]=AB_lds[b][1][1][t];
    }
    float v0[3][6], v1[3][6];
#pragma unroll
    for (int r=0;r<3;r++){
      const int yy=y-1+r;
      if ((unsigned)yy < (unsigned)IMG){
        const float* p0=x0+(size_t)yy*IMG;
        const float* p1=x1+(size_t)yy*IMG;
        const float4 m0=*(const float4*)(p0+xc);
        const float4 m1=*(const float4*)(p1+xc);
        v0[r][1]=m0.x; v0[r][2]=m0.y; v0[r][3]=m0.z; v0[r][4]=m0.w;
        v1[r][1]=m1.x; v1[r][2]=m1.y; v1[r][3]=m1.z; v1[r][4]=m1.w;
        v0[r][0]=(xc>0)?p0[xc-1]:0.f;        v1[r][0]=(xc>0)?p1[xc-1]:0.f;
        v0[r][5]=(xc+4<IMG)?p0[xc+4]:0.f;    v1[r][5]=(xc+4<IMG)?p1[xc+4]:0.f;
      } else {
#pragma unroll
        for (int c2=0;c2<6;c2++){v0[r][c2]=0.f;v1[r][c2]=0.f;}
      }
    }
    float res0[4], res1[4];
#pragma unroll
    for (int i=0;i<4;i++){
      float s0=v0[1][i+1];
      float s1=v1[1][i+1];
#pragma unroll
      for (int t=0;t<9;t++){
        const int ty=t/3, tx=t%3;
        const float g0=v0[ty][i+tx], g1=v1[ty][i+tx];
        s0 += A0[t]*g0 + B0[t]*g1;
        s1 += A1[t]*g0 + B1[t]*g1;
      }
      res0[i]=s0; res1[i]=s1;
    }
    float* o0p = out + ((size_t)(b*2+0)*IMG + y)*IMG + xc;
    float* o1p = out + ((size_t)(b*2+1)*IMG + y)*IMG + xc;
    *(float4*)o0p = make_float4(res0[0],res0[1],res0[2],res0[3]);
    *(float4*)o1p = make_float4(res1[0],res1[1],res1[2],res1[3]);
  }
}

extern "C" void kernel_launch(void* const* d_in, const int* in_sizes, int n_in,
                              void* d_out, int out_size, void* d_ws, size_t ws_size,
                              hipStream_t stream){
  const float* x       = (const float*)d_in[0];
  const float* e       = (const float*)d_in[1];
  const float* w_conv1 = (const float*)d_in[2];
  const float* w_dw    = (const float*)d_in[3];
  const float* w_ehead = (const float*)d_in[4];
  const float* w_proj  = (const float*)d_in[5];
  const float* a1      = (const float*)d_in[6];
  float* ws   = (float*)d_ws;
  float* part = ws;                              // 640*32 = 20480 floats
  unsigned int* bar = (unsigned int*)(ws + 20480);
  float* out  = (float*)d_out;

  hipMemsetAsync(bar, 0, sizeof(unsigned int), stream);
  hipLaunchKernelGGL(fused_kernel, dim3(NBLK), dim3(256), 0, stream,
                     x, e, w_conv1, w_dw, w_ehead, w_proj, a1, part, bar, out);
}

// Round 8
// 45.200 us; speedup vs baseline: 1.8655x; 1.4761x over previous
//
#include <hip/hip_runtime.h>

#define IMG 512
#define NPIX (IMG*IMG)

// ---------------------------------------------------------------------------
// K1: lag Gram partials. 320 blocks (2b x 5dy x 32 strips of 16 rows) x 512
// threads (4 row-slices x 128 col-groups of 4). Each thread: 4 row-steps,
// acc[6][5], 8-wave reduce. Output TRANSPOSED: part[slot][unit], slot=t*5+dxi
// (30), unit = b*160 + dyi*32 + strip  -> K2 reads 32 consecutive floats/row.
// ---------------------------------------------------------------------------
__global__ __launch_bounds__(512,2) void gram_kernel(const float* __restrict__ x,
                                                     const float* __restrict__ e,
                                                     float* __restrict__ part){
  const int unit = blockIdx.x;           // 0..319
  const int strip= unit & 31;
  const int dyi  = (unit >> 5) % 5;
  const int dy   = dyi - 2;
  const int b    = unit / 160;
  const int tid  = threadIdx.x;
  const int cx   = (tid & 127) << 2;
  const int r0   = (strip << 4) + ((tid >> 7) << 2);   // 4 rows per thread
  const float* x0 = x + (size_t)b*2*NPIX;
  const float* x1 = x0 + NPIX;
  const float* ep = e + (size_t)b*NPIX;

  float acc[6][5];
#pragma unroll
  for (int t=0;t<6;t++)
#pragma unroll
    for (int j=0;j<5;j++) acc[t][j]=0.f;

  const bool okL = (cx >= 4), okR = (cx < 508);

#pragma unroll 2
  for (int s=0;s<4;s++){
    const int r = r0+s;
    const float4 a0 = *(const float4*)(x0 + r*IMG + cx);
    const float4 a1v= *(const float4*)(x1 + r*IMG + cx);
    const float4 aE = *(const float4*)(ep + r*IMG + cx);
    const int rb = r+dy;
    if ((unsigned)rb < (unsigned)IMG){
      const float* p0 = x0 + rb*IMG;
      const float* p1 = x1 + rb*IMG;
      const float* pe = ep + rb*IMG;
      float w0[8], w1[8], wE[8];
      {
        const float4 z = make_float4(0.f,0.f,0.f,0.f);
        float4 L,M,R;
        L = okL ? *(const float4*)(p0+cx-4) : z;
        M = *(const float4*)(p0+cx);
        R = okR ? *(const float4*)(p0+cx+4) : z;
        w0[0]=L.z;w0[1]=L.w;w0[2]=M.x;w0[3]=M.y;w0[4]=M.z;w0[5]=M.w;w0[6]=R.x;w0[7]=R.y;
        L = okL ? *(const float4*)(p1+cx-4) : z;
        M = *(const float4*)(p1+cx);
        R = okR ? *(const float4*)(p1+cx+4) : z;
        w1[0]=L.z;w1[1]=L.w;w1[2]=M.x;w1[3]=M.y;w1[4]=M.z;w1[5]=M.w;w1[6]=R.x;w1[7]=R.y;
        L = okL ? *(const float4*)(pe+cx-4) : z;
        M = *(const float4*)(pe+cx);
        R = okR ? *(const float4*)(pe+cx+4) : z;
        wE[0]=L.z;wE[1]=L.w;wE[2]=M.x;wE[3]=M.y;wE[4]=M.z;wE[5]=M.w;wE[6]=R.x;wE[7]=R.y;
      }
#pragma unroll
      for (int j=0;j<5;j++){
        acc[0][j] += a0.x*w0[j] + a0.y*w0[j+1] + a0.z*w0[j+2] + a0.w*w0[j+3];
        acc[1][j] += a0.x*w1[j] + a0.y*w1[j+1] + a0.z*w1[j+2] + a0.w*w1[j+3];
        acc[2][j] += a1v.x*w1[j] + a1v.y*w1[j+1] + a1v.z*w1[j+2] + a1v.w*w1[j+3];
        acc[3][j] += a0.x*wE[j] + a0.y*wE[j+1] + a0.z*wE[j+2] + a0.w*wE[j+3];
        acc[4][j] += a1v.x*wE[j] + a1v.y*wE[j+1] + a1v.z*wE[j+2] + a1v.w*wE[j+3];
        acc[5][j] += aE.x*wE[j] + aE.y*wE[j+1] + aE.z*wE[j+2] + aE.w*wE[j+3];
      }
    }
  }

  __shared__ float red[8][30];
  const int wv   = tid >> 6;
  const int lane = tid & 63;
#pragma unroll
  for (int t=0;t<6;t++)
#pragma unroll
    for (int j=0;j<5;j++){
      float v = acc[t][j];
      for (int off=32; off; off>>=1) v += __shfl_down(v, off);
      if (lane==0) red[wv][t*5+j] = v;
    }
  __syncthreads();
  if (tid < 30){
    float s = red[0][tid]+red[1][tid]+red[2][tid]+red[3][tid]
            + red[4][tid]+red[5][tid]+red[6][tid]+red[7][tid];
    part[tid*320 + unit] = s;          // transposed: [slot][unit]
  }
}

// ---------------------------------------------------------------------------
// K2: fused attn + epilogue. 512 blocks x 256 threads. Every block redundantly
// reduces part (coalesced float4 runs) -> L -> attn -> folded 3x3 taps in LDS,
// then computes its 256 quad-pixels of out = x + conv3x3(x0;A) + conv3x3(x1;B).
// ---------------------------------------------------------------------------
__global__ __launch_bounds__(256,2) void attn_out_kernel(
    const float* __restrict__ x,
    const float* __restrict__ part,
    const float* __restrict__ w_conv1, const float* __restrict__ w_dw,
    const float* __restrict__ w_ehead, const float* __restrict__ w_proj,
    const float* __restrict__ a1,
    float* __restrict__ out)
{
  const int blk = blockIdx.x;
  const int tid = threadIdx.x;

  __shared__ float Lred[2][150];
  __shared__ float we_lds[128][9];
  __shared__ float nk_lds[2][128];
  __shared__ float attn_lds[2][8][16][16];
  __shared__ float M_lds[2][2][128];
  __shared__ float AB_lds[2][2][2][9];   // [b][o][A/B][tap]

  // ---- L reduction: each row = 32 consecutive floats = 8 float4 loads ----
  for (int i=tid; i<300; i+=256){
    const int bb=i/150, li=i%150;
    const int t=li/25, lag=li%25, dyi=lag/5, dxi=lag%5;
    const float4* p = (const float4*)(part + (t*5+dxi)*320 + bb*160 + dyi*32);
    float4 s4 = make_float4(0.f,0.f,0.f,0.f);
#pragma unroll
    for (int j=0;j<8;j++){
      const float4 v = p[j];
      s4.x += v.x; s4.y += v.y; s4.z += v.z; s4.w += v.w;
    }
    Lred[bb][li] = (s4.x+s4.y)+(s4.z+s4.w);
  }
  if (tid<128){
#pragma unroll
    for (int t=0;t<9;t++) we_lds[tid][t]=w_ehead[tid*9+t];
  }
  __syncthreads();

  const int b=tid>>7, h=(tid>>4)&7, c=tid&15;
  const int C=h*16+c;
  const float* Lb  = Lred[b];
  const float* L00=Lb, *L01=Lb+25, *L11=Lb+50, *L0e=Lb+75, *L1e=Lb+100, *Lee=Lb+125;

  float u[9], v[9];
  {
    const float wa=w_conv1[C*2+0], wb=w_conv1[C*2+1];
#pragma unroll
    for (int t=0;t<9;t++){ const float wd=w_dw[C*9+t]; u[t]=wd*wa; v[t]=wd*wb; }
  }
  float nq2=0.f, nk2=0.f;
#pragma unroll
  for (int t=0;t<9;t++){
    const int ty=t/3, tx=t%3;
#pragma unroll
    for (int t2=0;t2<9;t2++){
      const int dy=t2/3-ty, dx=t2%3-tx;
      const int di=( dy+2)*5+( dx+2);
      const int dj=(-dy+2)*5+(-dx+2);
      nq2 += u[t]*u[t2]*L00[di] + u[t]*v[t2]*L01[di] + v[t]*u[t2]*L01[dj] + v[t]*v[t2]*L11[di];
      nk2 += we_lds[C][t]*we_lds[C][t2]*Lee[di];
    }
  }
  nk_lds[b][C]=sqrtf(nk2);
  float P[9];
#pragma unroll
  for (int t2=0;t2<9;t2++){
    float s=0.f;
    const int t2y=t2/3, t2x=t2%3;
#pragma unroll
    for (int t=0;t<9;t++){
      const int di=(t2y-t/3+2)*5+(t2x-t%3+2);
      s += u[t]*L0e[di] + v[t]*L1e[di];
    }
    P[t2]=s;
  }
  __syncthreads();
  const float inv_nq = 1.f/fmaxf(sqrtf(nq2), 1e-12f);
  const float a1h=a1[h];
  float lg[16], mx=-1e30f;
#pragma unroll
  for (int d=0; d<16; d++){
    float S=0.f;
#pragma unroll
    for (int t2=0;t2<9;t2++) S += P[t2]*we_lds[h*16+d][t2];
    const float l = S*inv_nq/fmaxf(nk_lds[b][h*16+d],1e-12f)*a1h;
    lg[d]=l; mx=fmaxf(mx,l);
  }
  float sum=0.f;
#pragma unroll
  for (int d=0;d<16;d++){ lg[d]=expf(lg[d]-mx); sum+=lg[d]; }
  const float inv=1.f/sum;
#pragma unroll
  for (int d=0;d<16;d++) attn_lds[b][h][c][d]=lg[d]*inv;
  __syncthreads();
  for (int i=tid;i<512;i+=256){
    const int G=i&127, o=(i>>7)&1, bb=i>>8;
    const int hh=G>>4, dd=G&15;
    float s=0.f;
#pragma unroll
    for (int cc=0;cc<16;cc++) s += w_proj[o*128 + hh*16+cc]*attn_lds[bb][hh][cc][dd];
    M_lds[bb][o][G]=s;
  }
  __syncthreads();
  if (tid<36){
    const int t=tid%9, o=(tid/9)&1, bb=tid/18;
    float sa=0.f, sb=0.f;
    for (int G=0;G<128;G++){
      const float m=M_lds[bb][o][G];
      const float wd=w_dw[(128+G)*9+t];
      sa += m*wd*w_conv1[(128+G)*2+0];
      sb += m*wd*w_conv1[(128+G)*2+1];
    }
    AB_lds[bb][o][0][t] = sa;
    AB_lds[bb][o][1][t] = sb;
  }
  __syncthreads();

  // ----------------------------- epilogue conv -----------------------------
  {
    const int idx = blk*256 + tid;     // 131072 quad-pixels
    const int bq  = idx >> 16;
    const int y   = (idx >> 7) & (IMG-1);
    const int xc  = (idx & 127) << 2;
    const float* x0 = x + (size_t)bq*2*NPIX;
    const float* x1 = x0 + NPIX;

    float A0[9],A1[9],B0[9],B1[9];
#pragma unroll
    for (int t=0;t<9;t++){
      A0[t]=AB_lds[bq][0][0][t];  A1[t]=AB_lds[bq][1][0][t];
      B0[t]=AB_lds[bq][0][1][t];  B1[t]=AB_lds[bq][1][1][t];
    }
    float v0[3][6], v1[3][6];
#pragma unroll
    for (int r=0;r<3;r++){
      const int yy=y-1+r;
      if ((unsigned)yy < (unsigned)IMG){
        const float* p0=x0+(size_t)yy*IMG;
        const float* p1=x1+(size_t)yy*IMG;
        const float4 m0=*(const float4*)(p0+xc);
        const float4 m1=*(const float4*)(p1+xc);
        v0[r][1]=m0.x; v0[r][2]=m0.y; v0[r][3]=m0.z; v0[r][4]=m0.w;
        v1[r][1]=m1.x; v1[r][2]=m1.y; v1[r][3]=m1.z; v1[r][4]=m1.w;
        v0[r][0]=(xc>0)?p0[xc-1]:0.f;        v1[r][0]=(xc>0)?p1[xc-1]:0.f;
        v0[r][5]=(xc+4<IMG)?p0[xc+4]:0.f;    v1[r][5]=(xc+4<IMG)?p1[xc+4]:0.f;
      } else {
#pragma unroll
        for (int c2=0;c2<6;c2++){v0[r][c2]=0.f;v1[r][c2]=0.f;}
      }
    }
    float res0[4], res1[4];
#pragma unroll
    for (int i=0;i<4;i++){
      float s0=v0[1][i+1];
      float s1=v1[1][i+1];
#pragma unroll
      for (int t=0;t<9;t++){
        const int ty=t/3, tx=t%3;
        const float g0=v0[ty][i+tx], g1=v1[ty][i+tx];
        s0 += A0[t]*g0 + B0[t]*g1;
        s1 += A1[t]*g0 + B1[t]*g1;
      }
      res0[i]=s0; res1[i]=s1;
    }
    float* o0p = out + ((size_t)(bq*2+0)*IMG + y)*IMG + xc;
    float* o1p = out + ((size_t)(bq*2+1)*IMG + y)*IMG + xc;
    *(float4*)o0p = make_float4(res0[0],res0[1],res0[2],res0[3]);
    *(float4*)o1p = make_float4(res1[0],res1[1],res1[2],res1[3]);
  }
}

extern "C" void kernel_launch(void* const* d_in, const int* in_sizes, int n_in,
                              void* d_out, int out_size, void* d_ws, size_t ws_size,
                              hipStream_t stream){
  const float* x       = (const float*)d_in[0];
  const float* e       = (const float*)d_in[1];
  const float* w_conv1 = (const float*)d_in[2];
  const float* w_dw    = (const float*)d_in[3];
  const float* w_ehead = (const float*)d_in[4];
  const float* w_proj  = (const float*)d_in[5];
  const float* a1      = (const float*)d_in[6];
  float* part = (float*)d_ws;          // 30*320 = 9600 floats
  float* out  = (float*)d_out;

  hipLaunchKernelGGL(gram_kernel,     dim3(320), dim3(512), 0, stream, x, e, part);
  hipLaunchKernelGGL(attn_out_kernel, dim3(512), dim3(256), 0, stream, x, part,
                     w_conv1, w_dw, w_ehead, w_proj, a1, out);
}